// Round 2
// baseline (443.238 us; speedup 1.0000x reference)
//
#include <hip/hip_runtime.h>
#include <math.h>

#define S 2048
#define D 64
#define H 16
#define BR 64              // Q rows per block
#define BC 64              // K cols per tile
#define NIT (S / BC)       // 32 K-tiles
#define KSTR 72            // LDS row stride (ushorts) for Qs/Ks/Phi/Plo

// V^T staging layout (subtiled for ds_read_b64_tr_b16, bank-conflict-free):
//   element (k, d): dblock = d>>4, subtile = k>>2 (4 k-rows x 16 d, row-major)
//   ushort index = dblock*VT_DBLK + (k>>2)*VT_SUB + (k&3)*16 + (d&15)
//   VT_SUB = 72 ushorts (144 B: 128 B payload + 16 B pad -> quads spread banks)
//   VT_DBLK = 1184 ushorts (2368 B: 16*144 + 64 pad -> d-block parity spreads banks)
#define VT_SUB  72
#define VT_DBLK 1184
#define VT_SIZE (4 * VT_DBLK)    // 4736 ushorts = 9472 B

typedef __attribute__((ext_vector_type(8))) short bf16x8;
typedef __attribute__((ext_vector_type(4))) short bf16x4;
typedef __attribute__((ext_vector_type(4))) float f32x4;

__device__ __forceinline__ unsigned short f2bf(float x) {
    unsigned u = __float_as_uint(x);
    u += 0x7fffu + ((u >> 16) & 1u);          // RTNE
    return (unsigned short)(u >> 16);
}
__device__ __forceinline__ float bf2f(unsigned short h) {
    return __uint_as_float(((unsigned)h) << 16);
}

#define LGKM0() asm volatile("s_waitcnt lgkmcnt(0)" ::: "memory")
#define BAR()   __builtin_amdgcn_s_barrier()

// hardware-transpose LDS read: lane l of each 16-lane group gets column (l&15)
// of the 4x16 bf16 subtile covered by its group's 128B window (addr = base+l16*8)
template <int OFF>
__device__ __forceinline__ bf16x4 tr_read(unsigned addr) {
    bf16x4 d;
    asm volatile("ds_read_b64_tr_b16 %0, %1 offset:%c2"
                 : "=v"(d) : "v"(addr), "i"(OFF));
    return d;
}

template <int KS>
__device__ __forceinline__ void pv_step(const unsigned short* Phi_,
                                        const unsigned short* Plo_,
                                        int prow, int quad,
                                        unsigned a_hi, unsigned a_lo,
                                        f32x4* cacc) {
    bf16x8 ah = *(const bf16x8*)&Phi_[prow + KS * 32 + quad * 8];
    bf16x8 al = *(const bf16x8*)&Plo_[prow + KS * 32 + quad * 8];
    // V^T frags via hardware transpose: frag(vs) covers k = KS*32 + quad*8 + 0..7
    // subtile index = 8*KS + 2*quad (+1); quad folded into addr reg, rest immediate.
    bf16x4 th[8], tl[8];
#define TRPAIR(vs) \
    th[2*(vs)]   = tr_read<KS*1152 + (vs)*2368 +   0>(a_hi); \
    th[2*(vs)+1] = tr_read<KS*1152 + (vs)*2368 + 144>(a_hi); \
    tl[2*(vs)]   = tr_read<KS*1152 + (vs)*2368 +   0>(a_lo); \
    tl[2*(vs)+1] = tr_read<KS*1152 + (vs)*2368 + 144>(a_lo);
    TRPAIR(0) TRPAIR(1) TRPAIR(2) TRPAIR(3)
#undef TRPAIR
    LGKM0();
    __builtin_amdgcn_sched_barrier(0);   // rule 18: keep MFMAs below the wait
#pragma unroll
    for (int vs = 0; vs < 4; ++vs) {
        bf16x8 bh = __builtin_shufflevector(th[2*vs], th[2*vs+1], 0,1,2,3,4,5,6,7);
        bf16x8 bl = __builtin_shufflevector(tl[2*vs], tl[2*vs+1], 0,1,2,3,4,5,6,7);
        cacc[vs] = __builtin_amdgcn_mfma_f32_16x16x32_bf16(bh, ah, cacc[vs], 0, 0, 0);
        cacc[vs] = __builtin_amdgcn_mfma_f32_16x16x32_bf16(bl, ah, cacc[vs], 0, 0, 0);
        cacc[vs] = __builtin_amdgcn_mfma_f32_16x16x32_bf16(bh, al, cacc[vs], 0, 0, 0);
    }
}

__global__ __launch_bounds__(256, 2)
void k_attn_fused(const float* __restrict__ Q, const float* __restrict__ K,
                  const float* __restrict__ V, float* __restrict__ ctx,
                  float* __restrict__ attn) {
    __shared__ __align__(16) unsigned short Qs[BR * KSTR];    // 9216 B
    __shared__ __align__(16) unsigned short Ks[BC * KSTR];    // 9216 B
    __shared__ __align__(16) unsigned short Vthi[VT_SIZE];    // 9472 B (subtiled)
    __shared__ __align__(16) unsigned short Vtlo[VT_SIZE];    // 9472 B
    __shared__ __align__(16) unsigned short Phi[BR * KSTR];   // 9216 B
    __shared__ __align__(16) unsigned short Plo[BR * KSTR];   // 9216 B
    // total 55808 B -> 2 blocks/CU

    // XCD-clustered remap: each XCD (bid&7) owns 2 heads -> K/V set 2MB fits L2
    const int bid = blockIdx.x;
    const int idx_in = bid >> 3;
    const int h  = ((bid & 7) << 1) | (idx_in >> 5);
    const int r0 = (idx_in & 31) * BR;

    const int t  = threadIdx.x;
    const int w    = t >> 6;
    const int lane = t & 63;
    const int l16  = lane & 15;
    const int quad = lane >> 4;

    const float* Qh = Q + (size_t)h * S * D;
    const float* Kh = K + (size_t)h * S * D;
    const float* Vh = V + (size_t)h * S * D;

    // per-lane tr-read base: quad -> subtile*2 (2*144B), l16 -> 8B lane slot
    const unsigned lpart = (unsigned)(quad * 288 + l16 * 8);
    const unsigned a_vhi = (unsigned)(uintptr_t)&Vthi[0] + lpart;
    const unsigned a_vlo = (unsigned)(uintptr_t)&Vtlo[0] + lpart;

    // ---- stage Q tile (64x64 fp32 -> bf16 LDS), coalesced float4 ----
#pragma unroll
    for (int p = 0; p < 4; ++p) {
        int idx = t + p * 256;
        int r = idx >> 4, c4 = (idx & 15) * 4;
        float4 v = *(const float4*)(Qh + (size_t)(r0 + r) * D + c4);
        *(ushort4*)&Qs[r * KSTR + c4] =
            make_ushort4(f2bf(v.x), f2bf(v.y), f2bf(v.z), f2bf(v.w));
    }
    LGKM0(); BAR();

    bf16x8 bq[2];
    bq[0] = *(const bf16x8*)&Qs[(w * 16 + l16) * KSTR + 0 * 32 + quad * 8];
    bq[1] = *(const bf16x8*)&Qs[(w * 16 + l16) * KSTR + 1 * 32 + quad * 8];

    const f32x4 zero4 = {0.f, 0.f, 0.f, 0.f};
    float lsum = 0.f;

    // =================== Pass A: denominators ===================
    float4 kreg[4];
#pragma unroll
    for (int p = 0; p < 4; ++p) {
        int idx = t + p * 256;
        int r = idx >> 4, c4 = (idx & 15) * 4;
        kreg[p] = *(const float4*)(Kh + (size_t)r * D + c4);
    }
    for (int kt = 0; kt < NIT; ++kt) {
#pragma unroll
        for (int p = 0; p < 4; ++p) {
            int idx = t + p * 256;
            int r = idx >> 4, c4 = (idx & 15) * 4;
            *(ushort4*)&Ks[r * KSTR + c4] =
                make_ushort4(f2bf(kreg[p].x), f2bf(kreg[p].y), f2bf(kreg[p].z), f2bf(kreg[p].w));
        }
        LGKM0(); BAR();
        if (kt + 1 < NIT) {
#pragma unroll
            for (int p = 0; p < 4; ++p) {
                int idx = t + p * 256;
                int r = idx >> 4, c4 = (idx & 15) * 4;
                kreg[p] = *(const float4*)(Kh + (size_t)((kt + 1) * BC + r) * D + c4);
            }
        }
        f32x4 acc[4] = {zero4, zero4, zero4, zero4};
#pragma unroll
        for (int ks = 0; ks < 2; ++ks)
#pragma unroll
            for (int cs = 0; cs < 4; ++cs) {
                bf16x8 ak = *(const bf16x8*)&Ks[(cs * 16 + l16) * KSTR + ks * 32 + quad * 8];
                acc[cs] = __builtin_amdgcn_mfma_f32_16x16x32_bf16(ak, bq[ks], acc[cs], 0, 0, 0);
            }
        float e = 0.f;
#pragma unroll
        for (int cs = 0; cs < 4; ++cs)
#pragma unroll
            for (int r2 = 0; r2 < 4; ++r2)
                e += __expf(acc[cs][r2] * 0.125f);
        e += __shfl_xor(e, 16);
        e += __shfl_xor(e, 32);
        lsum += e;
        BAR();
    }
    const float linv = 1.0f / lsum;

    // =================== Pass B: attn write + P@V ===================
    f32x4 cacc[4] = {zero4, zero4, zero4, zero4};
    float4 vreg[4];
#pragma unroll
    for (int p = 0; p < 4; ++p) {
        int idx = t + p * 256;
        int r = idx >> 4, c4 = (idx & 15) * 4;
        kreg[p] = *(const float4*)(Kh + (size_t)r * D + c4);
        vreg[p] = *(const float4*)(Vh + (size_t)r * D + c4);
    }
    for (int kt = 0; kt < NIT; ++kt) {
        // stage K (row-major) + V (natural orientation, subtiled) from regs
#pragma unroll
        for (int p = 0; p < 4; ++p) {
            int idx = t + p * 256;
            int r = idx >> 4, c4 = (idx & 15) * 4;       // K: row,col ; V: k=r, d0=c4
            *(ushort4*)&Ks[r * KSTR + c4] =
                make_ushort4(f2bf(kreg[p].x), f2bf(kreg[p].y), f2bf(kreg[p].z), f2bf(kreg[p].w));
            unsigned short h0 = f2bf(vreg[p].x), h1 = f2bf(vreg[p].y),
                           h2 = f2bf(vreg[p].z), h3 = f2bf(vreg[p].w);
            int vtoff = (c4 >> 4) * VT_DBLK + (r >> 2) * VT_SUB + (r & 3) * 16 + (c4 & 15);
            *(ushort4*)&Vthi[vtoff] = make_ushort4(h0, h1, h2, h3);
            *(ushort4*)&Vtlo[vtoff] =
                make_ushort4(f2bf(vreg[p].x - bf2f(h0)), f2bf(vreg[p].y - bf2f(h1)),
                             f2bf(vreg[p].z - bf2f(h2)), f2bf(vreg[p].w - bf2f(h3)));
        }
        LGKM0(); BAR();
        if (kt + 1 < NIT) {
#pragma unroll
            for (int p = 0; p < 4; ++p) {
                int idx = t + p * 256;
                int r = idx >> 4, c4 = (idx & 15) * 4;
                kreg[p] = *(const float4*)(Kh + (size_t)((kt + 1) * BC + r) * D + c4);
                vreg[p] = *(const float4*)(Vh + (size_t)((kt + 1) * BC + r) * D + c4);
            }
        }
        // recompute S^T tile (swapped operands)
        f32x4 acc[4] = {zero4, zero4, zero4, zero4};
#pragma unroll
        for (int ks = 0; ks < 2; ++ks)
#pragma unroll
            for (int cs = 0; cs < 4; ++cs) {
                bf16x8 ak = *(const bf16x8*)&Ks[(cs * 16 + l16) * KSTR + ks * 32 + quad * 8];
                acc[cs] = __builtin_amdgcn_mfma_f32_16x16x32_bf16(ak, bq[ks], acc[cs], 0, 0, 0);
            }

        // normalize; f32x4 nontemporal attn store; b64 P staging [q][k]
        float* arow = attn + (size_t)(h * S + r0 + w * 16 + l16) * S + (size_t)kt * BC;
        const int prow = (w * 16 + l16) * KSTR;
#pragma unroll
        for (int cs = 0; cs < 4; ++cs) {
            f32x4 pv;
#pragma unroll
            for (int r2 = 0; r2 < 4; ++r2)
                pv[r2] = __expf(acc[cs][r2] * 0.125f) * linv;
            __builtin_nontemporal_store(pv, (f32x4*)(arow + cs * 16 + quad * 4));
            unsigned short h0 = f2bf(pv[0]), h1 = f2bf(pv[1]),
                           h2 = f2bf(pv[2]), h3 = f2bf(pv[3]);
            *(ushort4*)&Phi[prow + cs * 16 + quad * 4] = make_ushort4(h0, h1, h2, h3);
            *(ushort4*)&Plo[prow + cs * 16 + quad * 4] =
                make_ushort4(f2bf(pv[0] - bf2f(h0)), f2bf(pv[1] - bf2f(h1)),
                             f2bf(pv[2] - bf2f(h2)), f2bf(pv[3] - bf2f(h3)));
        }
        // P staging is intra-wave (rows w*16+l16 written & read only by wave w)
        asm volatile("" ::: "memory");

        pv_step<0>(Phi, Plo, prow, quad, a_vhi, a_vlo, cacc);
        pv_step<1>(Phi, Plo, prow, quad, a_vhi, a_vlo, cacc);

        BAR();   // protect Ks/Vt before next-tile restage
        asm volatile("" ::: "memory");
    }

    // epilogue: ctx store, f32x4 per lane
    float* crow = ctx + (size_t)(h * S + r0 + w * 16 + l16) * D;
#pragma unroll
    for (int vs = 0; vs < 4; ++vs)
        *(f32x4*)(crow + vs * 16 + quad * 4) = cacc[vs];
}

extern "C" void kernel_launch(void* const* d_in, const int* in_sizes, int n_in,
                              void* d_out, int out_size, void* d_ws, size_t ws_size,
                              hipStream_t stream) {
    (void)in_sizes; (void)n_in; (void)d_ws; (void)ws_size; (void)out_size;
    const float* Q = (const float*)d_in[0];
    const float* K = (const float*)d_in[1];
    const float* V = (const float*)d_in[2];
    float* ctx  = (float*)d_out;                          // [16,2048,64]
    float* attn = (float*)d_out + (size_t)H * S * D;      // [16,2048,2048]

    k_attn_fused<<<dim3((S / BR) * H), 256, 0, stream>>>(Q, K, V, ctx, attn);
}

// Round 3
// 376.748 us; speedup vs baseline: 1.1765x; 1.1765x over previous
//
#include <hip/hip_runtime.h>
#include <math.h>

#define S 2048
#define D 64
#define H 16
#define BR 64              // Q rows per block
#define BC 64              // K cols per tile
#define NIT (S / BC)       // 32 K-tiles
#define KSTR 72            // Qs/Ks/Phi/Plo row stride (ushorts): min-conflict b128 reads
#define VSTR 88            // Vt row stride (ushorts) = 176 B: writes 2-way, b128 reads min
#define ASTR 36            // As row stride (floats) = 144 B: both sides min-conflict

typedef __attribute__((ext_vector_type(8))) short bf16x8;
typedef __attribute__((ext_vector_type(4))) float f32x4;

__device__ __forceinline__ unsigned short f2bf(float x) {
    unsigned u = __float_as_uint(x);
    u += 0x7fffu + ((u >> 16) & 1u);          // RTNE
    return (unsigned short)(u >> 16);
}
__device__ __forceinline__ float bf2f(unsigned short h) {
    return __uint_as_float(((unsigned)h) << 16);
}

#define LGKM0() asm volatile("s_waitcnt lgkmcnt(0)" ::: "memory")
#define BAR()   __builtin_amdgcn_s_barrier()

__global__ __launch_bounds__(256, 2)
void k_attn_fused(const float* __restrict__ Q, const float* __restrict__ K,
                  const float* __restrict__ V, float* __restrict__ ctx,
                  float* __restrict__ attn) {
    __shared__ __align__(16) unsigned short Qs[BR * KSTR];    // 9216 B; reused as As (f32) in pass B
    __shared__ __align__(16) unsigned short Ks[BC * KSTR];    // 9216 B
    __shared__ __align__(16) unsigned short Vthi[D * VSTR];   // 11264 B  Vt[d][k], reg-transposed
    __shared__ __align__(16) unsigned short Vtlo[D * VSTR];   // 11264 B
    __shared__ __align__(16) unsigned short Phi[BR * KSTR];   // 9216 B
    __shared__ __align__(16) unsigned short Plo[BR * KSTR];   // 9216 B
    // total 59392 B -> 2 blocks/CU
    float* As = (float*)Qs;   // attn staging tile [64][ASTR]; Qs is dead after bq load

    // XCD-clustered remap: each XCD (bid&7) owns 2 heads -> K/V set 2MB fits its L2
    const int bid = blockIdx.x;
    const int idx_in = bid >> 3;
    const int h  = ((bid & 7) << 1) | (idx_in >> 5);
    const int r0 = (idx_in & 31) * BR;

    const int t  = threadIdx.x;
    const int w    = t >> 6;
    const int lane = t & 63;
    const int l16  = lane & 15;
    const int quad = lane >> 4;

    const float* Qh = Q + (size_t)h * S * D;
    const float* Kh = K + (size_t)h * S * D;
    const float* Vh = V + (size_t)h * S * D;

    // ---- stage Q tile (64x64 fp32 -> bf16 LDS), coalesced float4 ----
#pragma unroll
    for (int p = 0; p < 4; ++p) {
        int idx = t + p * 256;
        int r = idx >> 4, c4 = (idx & 15) * 4;
        float4 v = *(const float4*)(Qh + (size_t)(r0 + r) * D + c4);
        *(ushort4*)&Qs[r * KSTR + c4] =
            make_ushort4(f2bf(v.x), f2bf(v.y), f2bf(v.z), f2bf(v.w));
    }
    LGKM0(); BAR();

    bf16x8 bq[2];
    bq[0] = *(const bf16x8*)&Qs[(w * 16 + l16) * KSTR + 0 * 32 + quad * 8];
    bq[1] = *(const bf16x8*)&Qs[(w * 16 + l16) * KSTR + 1 * 32 + quad * 8];

    const f32x4 zero4 = {0.f, 0.f, 0.f, 0.f};
    float lsum = 0.f;

    // =================== Pass A: denominators ===================
    float4 kreg[4];
#pragma unroll
    for (int p = 0; p < 4; ++p) {
        int idx = t + p * 256;
        int r = idx >> 4, c4 = (idx & 15) * 4;
        kreg[p] = *(const float4*)(Kh + (size_t)r * D + c4);
    }
    for (int kt = 0; kt < NIT; ++kt) {
#pragma unroll
        for (int p = 0; p < 4; ++p) {
            int idx = t + p * 256;
            int r = idx >> 4, c4 = (idx & 15) * 4;
            *(ushort4*)&Ks[r * KSTR + c4] =
                make_ushort4(f2bf(kreg[p].x), f2bf(kreg[p].y), f2bf(kreg[p].z), f2bf(kreg[p].w));
        }
        LGKM0(); BAR();
        if (kt + 1 < NIT) {
#pragma unroll
            for (int p = 0; p < 4; ++p) {
                int idx = t + p * 256;
                int r = idx >> 4, c4 = (idx & 15) * 4;
                kreg[p] = *(const float4*)(Kh + (size_t)((kt + 1) * BC + r) * D + c4);
            }
        }
        f32x4 acc[4] = {zero4, zero4, zero4, zero4};
#pragma unroll
        for (int ks = 0; ks < 2; ++ks)
#pragma unroll
            for (int cs = 0; cs < 4; ++cs) {
                bf16x8 ak = *(const bf16x8*)&Ks[(cs * 16 + l16) * KSTR + ks * 32 + quad * 8];
                acc[cs] = __builtin_amdgcn_mfma_f32_16x16x32_bf16(ak, bq[ks], acc[cs], 0, 0, 0);
            }
        float e = 0.f;
#pragma unroll
        for (int cs = 0; cs < 4; ++cs)
#pragma unroll
            for (int r2 = 0; r2 < 4; ++r2)
                e += __expf(acc[cs][r2] * 0.125f);
        e += __shfl_xor(e, 16);
        e += __shfl_xor(e, 32);
        lsum += e;
        BAR();
    }
    const float linv = 1.0f / lsum;

    // =================== Pass B: attn write + P@V ===================
    f32x4 cacc[4] = {zero4, zero4, zero4, zero4};
    // V prefetch: thread owns d=lane, k = w*16 + p*4 + i  (coalesced: one V row / wave-instr)
    float vr[16];
#pragma unroll
    for (int p = 0; p < 4; ++p) {
        int idx = t + p * 256;
        int r = idx >> 4, c4 = (idx & 15) * 4;
        kreg[p] = *(const float4*)(Kh + (size_t)r * D + c4);
#pragma unroll
        for (int i = 0; i < 4; ++i)
            vr[p * 4 + i] = Vh[(size_t)(w * 16 + p * 4 + i) * D + lane];
    }
    for (int kt = 0; kt < NIT; ++kt) {
        // stage K (row-major) + Vt[d][k] via register transpose: ushort4 per p
#pragma unroll
        for (int p = 0; p < 4; ++p) {
            int idx = t + p * 256;
            int r = idx >> 4, c4 = (idx & 15) * 4;
            *(ushort4*)&Ks[r * KSTR + c4] =
                make_ushort4(f2bf(kreg[p].x), f2bf(kreg[p].y), f2bf(kreg[p].z), f2bf(kreg[p].w));
            const int kb = w * 16 + p * 4;
            unsigned short h0 = f2bf(vr[p * 4 + 0]), h1 = f2bf(vr[p * 4 + 1]),
                           h2 = f2bf(vr[p * 4 + 2]), h3 = f2bf(vr[p * 4 + 3]);
            *(ushort4*)&Vthi[lane * VSTR + kb] = make_ushort4(h0, h1, h2, h3);
            *(ushort4*)&Vtlo[lane * VSTR + kb] =
                make_ushort4(f2bf(vr[p * 4 + 0] - bf2f(h0)), f2bf(vr[p * 4 + 1] - bf2f(h1)),
                             f2bf(vr[p * 4 + 2] - bf2f(h2)), f2bf(vr[p * 4 + 3] - bf2f(h3)));
        }
        LGKM0(); BAR();
        if (kt + 1 < NIT) {
#pragma unroll
            for (int p = 0; p < 4; ++p) {
                int idx = t + p * 256;
                int r = idx >> 4, c4 = (idx & 15) * 4;
                kreg[p] = *(const float4*)(Kh + (size_t)((kt + 1) * BC + r) * D + c4);
#pragma unroll
                for (int i = 0; i < 4; ++i)
                    vr[p * 4 + i] = Vh[(size_t)((kt + 1) * BC + w * 16 + p * 4 + i) * D + lane];
            }
        }
        // QK^T (swapped): lane owns k = cs*16+quad*4+reg at q = w*16+l16
        f32x4 acc[4] = {zero4, zero4, zero4, zero4};
#pragma unroll
        for (int ks = 0; ks < 2; ++ks)
#pragma unroll
            for (int cs = 0; cs < 4; ++cs) {
                bf16x8 ak = *(const bf16x8*)&Ks[(cs * 16 + l16) * KSTR + ks * 32 + quad * 8];
                acc[cs] = __builtin_amdgcn_mfma_f32_16x16x32_bf16(ak, bq[ks], acc[cs], 0, 0, 0);
            }

        // softmax -> P staging + attn out via LDS bounce (full-line stores)
        const int prow = (w * 16 + l16) * KSTR;
#pragma unroll
        for (int half = 0; half < 2; ++half) {
#pragma unroll
            for (int csr = 0; csr < 2; ++csr) {
                const int cs = half * 2 + csr;
                f32x4 pv;
#pragma unroll
                for (int r2 = 0; r2 < 4; ++r2)
                    pv[r2] = __expf(acc[cs][r2] * 0.125f) * linv;
                *(f32x4*)&As[(w * 16 + l16) * ASTR + csr * 16 + quad * 4] = pv;
                unsigned short h0 = f2bf(pv[0]), h1 = f2bf(pv[1]),
                               h2 = f2bf(pv[2]), h3 = f2bf(pv[3]);
                *(ushort4*)&Phi[prow + cs * 16 + quad * 4] = make_ushort4(h0, h1, h2, h3);
                *(ushort4*)&Plo[prow + cs * 16 + quad * 4] =
                    make_ushort4(f2bf(pv[0] - bf2f(h0)), f2bf(pv[1] - bf2f(h1)),
                                 f2bf(pv[2] - bf2f(h2)), f2bf(pv[3] - bf2f(h3)));
            }
            // readout: 8 rows x 128 B per wave-instruction -> full HBM lines
#pragma unroll
            for (int i = 0; i < 2; ++i) {
                const int row = w * 16 + (lane >> 3) + 8 * i;
                f32x4 tv = *(const f32x4*)&As[row * ASTR + (lane & 7) * 4];
                __builtin_nontemporal_store(
                    tv, (f32x4*)(attn + (size_t)(h * S + r0 + row) * S +
                                 (size_t)kt * BC + half * 32 + (lane & 7) * 4));
            }
        }

        // P @ V (swapped): cacc[vs] over d = vs*16+quad*4+reg at q = w*16+l16
#pragma unroll
        for (int ks = 0; ks < 2; ++ks) {
            bf16x8 ah = *(const bf16x8*)&Phi[prow + ks * 32 + quad * 8];
            bf16x8 al = *(const bf16x8*)&Plo[prow + ks * 32 + quad * 8];
#pragma unroll
            for (int vs = 0; vs < 4; ++vs) {
                bf16x8 bh = *(const bf16x8*)&Vthi[(vs * 16 + l16) * VSTR + ks * 32 + quad * 8];
                bf16x8 bl = *(const bf16x8*)&Vtlo[(vs * 16 + l16) * VSTR + ks * 32 + quad * 8];
                cacc[vs] = __builtin_amdgcn_mfma_f32_16x16x32_bf16(bh, ah, cacc[vs], 0, 0, 0);
                cacc[vs] = __builtin_amdgcn_mfma_f32_16x16x32_bf16(bl, ah, cacc[vs], 0, 0, 0);
                cacc[vs] = __builtin_amdgcn_mfma_f32_16x16x32_bf16(bh, al, cacc[vs], 0, 0, 0);
            }
        }
        BAR();   // protect Ks/Vt/As/P before next-tile restage
    }

    // epilogue: ctx store, f32x4 per lane
    float* crow = ctx + (size_t)(h * S + r0 + w * 16 + l16) * D;
#pragma unroll
    for (int vs = 0; vs < 4; ++vs)
        *(f32x4*)(crow + vs * 16 + quad * 4) = cacc[vs];
}

extern "C" void kernel_launch(void* const* d_in, const int* in_sizes, int n_in,
                              void* d_out, int out_size, void* d_ws, size_t ws_size,
                              hipStream_t stream) {
    (void)in_sizes; (void)n_in; (void)d_ws; (void)ws_size; (void)out_size;
    const float* Q = (const float*)d_in[0];
    const float* K = (const float*)d_in[1];
    const float* V = (const float*)d_in[2];
    float* ctx  = (float*)d_out;                          // [16,2048,64]
    float* attn = (float*)d_out + (size_t)H * S * D;      // [16,2048,2048]

    k_attn_fused<<<dim3((S / BR) * H), 256, 0, stream>>>(Q, K, V, ctx, attn);
}